// Round 16
// baseline (602.888 us; speedup 1.0000x reference)
//
#include <hip/hip_runtime.h>
#include <hip/hip_bf16.h>
#include <hip/hip_fp16.h>

#define BATCH 16384
#define HID   2048
#define IND   784
#define INDP  896   // 784 padded to 14*64 (even # of 64-wide K-tiles)
#define OUTD  10

typedef _Float16 f16;
typedef __attribute__((ext_vector_type(8))) _Float16 f16x8;
typedef __attribute__((ext_vector_type(4))) _Float16 f16x4;
typedef __attribute__((ext_vector_type(4))) float f32x4;

// ---- fused segmented prep (R13/R14, verified) ------------------------------
struct PrepArgs {
    const float* src[6];
    const void*  mk[6];
    f16*         dst[6];
    long         off4[7];
    int          rin[6], kin[6], kout[6];
};

__global__ void prep_fused(PrepArgs a, long total4) {
    long idx = (long)blockIdx.x * blockDim.x + threadIdx.x;
    if (idx >= total4) return;
    int s = 0;
    #pragma unroll
    for (int i = 1; i < 6; ++i) s += (idx >= a.off4[i]);
    long li = idx - a.off4[s];
    int kout = a.kout[s], kin = a.kin[s], rin = a.rin[s];
    int k4 = kout >> 2;
    int r = (int)(li / k4), c = (int)(li - (long)r * k4) << 2;
    f16x4 o = {};
    if (r < rin && c < kin) {
        float4 v = *(const float4*)(a.src[s] + (size_t)r * kin + c);
        float vv0 = v.x, vv1 = v.y, vv2 = v.z, vv3 = v.w;
        if (a.mk[s]) {
            uint4 m = *(const uint4*)((const unsigned int*)a.mk[s] + (size_t)r * kin + c);
            if (!m.x) vv0 = 0.f; if (!m.y) vv1 = 0.f;
            if (!m.z) vv2 = 0.f; if (!m.w) vv3 = 0.f;
        }
        o[0] = (f16)vv0; o[1] = (f16)vv1; o[2] = (f16)vv2; o[3] = (f16)vv3;
    }
    *(f16x4*)(a.dst[s] + (size_t)r * kout + c) = o;
}

__device__ __forceinline__ void gload_lds16(const f16* g, f16* l) {
    __builtin_amdgcn_global_load_lds(
        (const __attribute__((address_space(1))) unsigned int*)g,
        (__attribute__((address_space(3))) unsigned int*)l,
        16, 0, 0);
}

#define BAR()    __builtin_amdgcn_s_barrier()
#define SCHED()  __builtin_amdgcn_sched_barrier(0)
#define WAITV4() asm volatile("s_waitcnt vmcnt(4)" ::: "memory")
#define WAITV8() asm volatile("s_waitcnt vmcnt(8)" ::: "memory")

// ---- 128x128 8-phase GEMM, R14 straddle at 2 blocks/CU (R16) ---------------
// R14 (256^2, 128 KB LDS) = 1 block/CU -> LDS & MFMA pipes fully serialized
// (120 us = 53 LDS + 66 MFMA floors). This kernel: same verified straddle
// schedule / swizzle / vmcnt ledger, 128^2 tile, 4 waves (2x2, wave-tile
// 64x64), panels [buf][ks][128][32] = 64 KB total -> 2 independent blocks/CU
// (decoupled barriers = m97/m114 implicit TLP overlap). No setprio (R14).
// Panel topology identical to R14 (2 gloads/stage/wave) -> same ledger:
// vmcnt(4) at even phases; stage drains 2 phases before first read.
template<bool RELU>
__global__ __launch_bounds__(256, 2) void gemm128(
    const f16* __restrict__ A, const f16* __restrict__ B,
    const float* __restrict__ bias, f16* __restrict__ C,
    int N, int K) {
    __shared__ f16 As[2 * 2 * 128 * 32];   // panels (buf,ks): [128][32] f16
    __shared__ f16 Bs[2 * 2 * 128 * 32];

    int nbn = N >> 7;
    int nwg = gridDim.x;
    int cpx = nwg >> 3;                       // nwg % 8 == 0
    int bid = blockIdx.x;
    int swz = (bid & 7) * cpx + (bid >> 3);   // XCD-aware, bijective
    int bm = swz / nbn, bn = swz % nbn;

    int tid = threadIdx.x;
    int w = tid >> 6, lane = tid & 63;
    int wr = w >> 1, wc = w & 1;              // 2M x 2N, wave-tile 64x64
    int l15 = lane & 15, l4 = lane >> 4;

    const f16* Ag = A + (size_t)bm * 128 * K;
    const f16* Bg = B + (size_t)bn * 128 * K;

    // staging: wave w issue j covers rows (j*4+w)*16 + (lane>>2), slot lane&3.
    // (row>>1)&3 == (lane>>3)&3 (w*8, 32j vanish mod 4) -> pre-swizzled
    // global col-slot = (lane&3) ^ ((lane>>3)&3). LDS linear, wave-uniform.
    int srow = w * 16 + (lane >> 2);
    int gcol = ((lane & 3) ^ ((lane >> 3) & 3)) * 8;

    auto stageA = [&](int buf, int ks, int tk) {
        f16* l = As + (buf * 2 + ks) * 4096 + w * 512;
        gload_lds16(Ag + (size_t)srow * K + tk * 64 + ks * 32 + gcol, l);
        gload_lds16(Ag + (size_t)(srow + 64) * K + tk * 64 + ks * 32 + gcol, l + 2048);
    };
    auto stageB = [&](int buf, int ks, int tk) {
        f16* l = Bs + (buf * 2 + ks) * 4096 + w * 512;
        gload_lds16(Bg + (size_t)srow * K + tk * 64 + ks * 32 + gcol, l);
        gload_lds16(Bg + (size_t)(srow + 64) * K + tk * 64 + ks * 32 + gcol, l + 2048);
    };

    // frag reads: row = base16 + l15 -> (row>>1)&3 == (l15>>1)&3; R11-verified
    // conflict-free slot = l4 ^ ((l15>>1)&3).
    int rsw = (l4 ^ ((l15 >> 1) & 3)) * 8;
    auto ldA = [&](f16x8 (&af)[4], int buf, int ks) {
        int base = (buf * 2 + ks) * 4096;
        #pragma unroll
        for (int m = 0; m < 4; ++m) {
            int row = wr * 64 + m * 16 + l15;
            af[m] = *(const f16x8*)(As + base + row * 32 + rsw);
        }
    };
    auto ldB = [&](f16x8 (&bf)[2], int buf, int ks, int nh) {
        int base = (buf * 2 + ks) * 4096;
        #pragma unroll
        for (int n = 0; n < 2; ++n) {
            int row = wc * 64 + nh * 32 + n * 16 + l15;
            bf[n] = *(const f16x8*)(Bs + base + row * 32 + rsw);
        }
    };

    f32x4 acc[4][4] = {};
    auto mma = [&](f16x8 (&af)[4], f16x8 (&bf)[2], int nh) {
        #pragma unroll
        for (int m = 0; m < 4; ++m)
            #pragma unroll
            for (int n = 0; n < 2; ++n)
                acc[m][nh * 2 + n] = __builtin_amdgcn_mfma_f32_16x16x32_f16(
                    af[m], bf[n], acc[m][nh * 2 + n], 0, 0, 0);
    };

    int NT = K >> 6, NI = NT >> 1;

    // frag sets: A sets span 2 phases (one per (buf,ks) panel); B sets 1 phase.
    f16x8 Aa[4], Ab[4], Ba[2], Bb[2];

    // prologue: stage (0,0),(0,1),(1,0); vmcnt(8) drains (0,0); read its
    // frags; vmcnt(4) drains (0,1). Entering loop: outstanding = (1,0)'s 4.
    stageA(0, 0, 0); stageB(0, 0, 0); stageA(0, 1, 0); stageB(0, 1, 0);
    stageA(1, 0, 1); stageB(1, 0, 1);
    WAITV8(); SCHED(); BAR();
    ldA(Aa, 0, 0); ldB(Ba, 0, 0, 0); ldB(Bb, 0, 0, 1);
    WAITV4(); SCHED(); BAR();

    for (int it = 0; it < NI; ++it) {
        int t1 = 2 * it + 1, t2 = 2 * it + 2, t3 = 2 * it + 3;
        if (t2 >= NT) t2 = 0;   // tail: stage into retired panels, never read
        if (t3 >= NT) t3 = 0;

        // p1: (0,0,nh0)[Aa,Ba] | rd Ab<-(0,1), Ba<-(0,1,n0) | stage A(1,1)<-t1
        mma(Aa, Ba, 0);
        ldA(Ab, 0, 1); ldB(Ba, 0, 1, 0); stageA(1, 1, t1);
        SCHED(); BAR();
        // p2: (0,0,nh1)[Aa,Bb] | rd Bb<-(0,1,n1) | stage B(1,1)<-t1 | vmcnt
        mma(Aa, Bb, 1);
        ldB(Bb, 0, 1, 1); stageB(1, 1, t1);
        WAITV4(); SCHED(); BAR();
        // p3: (0,1,nh0)[Ab,Ba] | rd Aa<-(1,0), Ba<-(1,0,n0) | stage A(0,0)<-t2
        mma(Ab, Ba, 0);
        ldA(Aa, 1, 0); ldB(Ba, 1, 0, 0); stageA(0, 0, t2);
        SCHED(); BAR();
        // p4: (0,1,nh1)[Ab,Bb] | rd Bb<-(1,0,n1) | stage B(0,0)<-t2 | vmcnt
        mma(Ab, Bb, 1);
        ldB(Bb, 1, 0, 1); stageB(0, 0, t2);
        WAITV4(); SCHED(); BAR();
        // p5: (1,0,nh0)[Aa,Ba] | rd Ab<-(1,1), Ba<-(1,1,n0) | stage A(0,1)<-t2
        mma(Aa, Ba, 0);
        ldA(Ab, 1, 1); ldB(Ba, 1, 1, 0); stageA(0, 1, t2);
        SCHED(); BAR();
        // p6: (1,0,nh1)[Aa,Bb] | rd Bb<-(1,1,n1) | stage B(0,1)<-t2 | vmcnt
        mma(Aa, Bb, 1);
        ldB(Bb, 1, 1, 1); stageB(0, 1, t2);
        WAITV4(); SCHED(); BAR();
        // p7: (1,1,nh0)[Ab,Ba] | rd Aa<-(0,0)@t2, Ba<-(0,0,n0) | stage A(1,0)<-t3
        mma(Ab, Ba, 0);
        ldA(Aa, 0, 0); ldB(Ba, 0, 0, 0); stageA(1, 0, t3);
        SCHED(); BAR();
        // p8: (1,1,nh1)[Ab,Bb] | rd Bb<-(0,0,n1) | stage B(1,0)<-t3 | vmcnt
        mma(Ab, Bb, 1);
        ldB(Bb, 0, 0, 1); stageB(1, 0, t3);
        WAITV4(); SCHED(); BAR();
    }

    // epilogue: C/D layout col=lane&15, row=(lane>>4)*4+reg (m89/m91)
    #pragma unroll
    for (int nf = 0; nf < 4; ++nf) {
        int j = bn * 128 + wc * 64 + nf * 16 + l15;
        float bv = bias[j];
        #pragma unroll
        for (int mf = 0; mf < 4; ++mf) {
            int i0 = bm * 128 + wr * 64 + mf * 16 + l4 * 4;
            #pragma unroll
            for (int r = 0; r < 4; ++r) {
                float v = acc[mf][nf][r] + bv;
                if (RELU) v = fmaxf(v, 0.f);
                C[(size_t)(i0 + r) * N + j] = (f16)v;
            }
        }
    }
}

// ---- head: verified R5 128^2 kernel (Nout=10 guard, f32 out) ---------------
__global__ __launch_bounds__(256, 3) void gemm_head(
    const f16* __restrict__ A, const f16* __restrict__ B,
    const float* __restrict__ bias, float* __restrict__ C,
    int K, int Nout) {
    __shared__ f16 As[128 * 64];
    __shared__ f16 Bs[128 * 64];
    int bm = blockIdx.x;
    int t = threadIdx.x;
    int w = t >> 6, lane = t & 63;
    int wm = w >> 1, wn = w & 1;
    int l15 = lane & 15, l4 = lane >> 4;
    const f16* Ag = A + (size_t)bm * 128 * K;
    const f16* Bg = B;
    int rr = w * 8 + (lane >> 3);
    int cc = (lane & 7) * 8;
    f32x4 acc[4][4] = {};
    for (int k0 = 0; k0 < K; k0 += 64) {
        #pragma unroll
        for (int i = 0; i < 4; ++i)
            gload_lds16(Ag + (size_t)(i * 32 + rr) * K + k0 + cc, As + i * 2048 + w * 512);
        #pragma unroll
        for (int i = 0; i < 4; ++i)
            gload_lds16(Bg + (size_t)(i * 32 + rr) * K + k0 + cc, Bs + i * 2048 + w * 512);
        __syncthreads();
        #pragma unroll
        for (int ks = 0; ks < 2; ++ks) {
            f16x8 af[4], bfr[4];
            #pragma unroll
            for (int m = 0; m < 4; ++m)
                af[m] = *(const f16x8*)(As + (wm * 64 + m * 16 + l15) * 64 + ks * 32 + l4 * 8);
            #pragma unroll
            for (int n = 0; n < 4; ++n)
                bfr[n] = *(const f16x8*)(Bs + (wn * 64 + n * 16 + l15) * 64 + ks * 32 + l4 * 8);
            #pragma unroll
            for (int m = 0; m < 4; ++m)
                #pragma unroll
                for (int n = 0; n < 4; ++n)
                    acc[m][n] = __builtin_amdgcn_mfma_f32_16x16x32_f16(af[m], bfr[n], acc[m][n], 0, 0, 0);
        }
        __syncthreads();
    }
    #pragma unroll
    for (int n = 0; n < 4; ++n) {
        int j = wn * 64 + n * 16 + l15;
        bool jok = j < Nout;
        float bv = jok ? bias[j] : 0.f;
        #pragma unroll
        for (int m = 0; m < 4; ++m) {
            int i0 = bm * 128 + wm * 64 + m * 16 + l4 * 4;
            #pragma unroll
            for (int r = 0; r < 4; ++r) {
                if (jok) C[(size_t)(i0 + r) * Nout + j] = acc[m][n][r] + bv;
            }
        }
    }
}

extern "C" void kernel_launch(void* const* d_in, const int* in_sizes, int n_in,
                              void* d_out, int out_size, void* d_ws, size_t ws_size,
                              hipStream_t stream) {
    const float* x  = (const float*)d_in[0];
    const float* W1 = (const float*)d_in[1];
    const float* b1 = (const float*)d_in[2];
    const float* W2 = (const float*)d_in[3];
    const float* b2 = (const float*)d_in[4];
    const float* W3 = (const float*)d_in[5];
    const float* b3 = (const float*)d_in[6];
    const float* W4 = (const float*)d_in[7];
    const float* b4 = (const float*)d_in[8];
    const float* W5 = (const float*)d_in[9];
    const float* b5 = (const float*)d_in[10];
    const void* m1 = d_in[11];
    const void* m2 = d_in[12];
    const void* m3 = d_in[13];
    const void* m4 = d_in[14];

    char* ws = (char*)d_ws;
    size_t off = 0;
    auto alloc = [&](size_t b) { char* p = ws + off; off += (b + 255) & ~(size_t)255; return p; };
    f16* xb  = (f16*)alloc((size_t)BATCH * INDP * 2);
    f16* w1b = (f16*)alloc((size_t)HID * INDP * 2);
    f16* w2b = (f16*)alloc((size_t)HID * HID * 2);
    f16* w3b = (f16*)alloc((size_t)HID * HID * 2);
    f16* w4b = (f16*)alloc((size_t)HID * HID * 2);
    f16* w5b = (f16*)alloc((size_t)128 * HID * 2);
    f16* h1  = (f16*)alloc((size_t)BATCH * HID * 2);
    f16* h2  = (f16*)alloc((size_t)BATCH * HID * 2);

    PrepArgs pa;
    auto seg = [&](int i, const float* s, const void* mk, f16* d,
                   int rin, int kin, int kout) {
        pa.src[i] = s; pa.mk[i] = mk; pa.dst[i] = d;
        pa.rin[i] = rin; pa.kin[i] = kin; pa.kout[i] = kout;
    };
    seg(0, x,  nullptr, xb,  BATCH, IND, INDP);
    seg(1, W1, m1,      w1b, HID,   IND, INDP);
    seg(2, W2, m2,      w2b, HID,   HID, HID);
    seg(3, W3, m3,      w3b, HID,   HID, HID);
    seg(4, W4, m4,      w4b, HID,   HID, HID);
    seg(5, W5, nullptr, w5b, OUTD,  HID, HID);
    long rout[6] = {BATCH, HID, HID, HID, HID, 128};
    long acc4 = 0;
    for (int i = 0; i < 6; ++i) { pa.off4[i] = acc4; acc4 += rout[i] * (pa.kout[i] >> 2); }
    pa.off4[6] = acc4;
    int pgrid = (int)((acc4 + 255) / 256);
    prep_fused<<<pgrid, 256, 0, stream>>>(pa, acc4);

    int g = (BATCH / 128) * (HID / 128);   // 128 * 16 = 2048 blocks
    gemm128<true><<<g, 256, 0, stream>>>(xb, w1b, b1, h1, HID, INDP);
    gemm128<true><<<g, 256, 0, stream>>>(h1, w2b, b2, h2, HID, HID);
    gemm128<true><<<g, 256, 0, stream>>>(h2, w3b, b3, h1, HID, HID);
    gemm128<true><<<g, 256, 0, stream>>>(h1, w4b, b4, h2, HID, HID);
    gemm_head<<<BATCH / 128, 256, 0, stream>>>(h2, w5b, b5, (float*)d_out, HID, OUTD);
}

// Round 17
// 507.600 us; speedup vs baseline: 1.1877x; 1.1877x over previous
//
#include <hip/hip_runtime.h>
#include <hip/hip_bf16.h>
#include <hip/hip_fp16.h>

#define BATCH 16384
#define HID   2048
#define IND   784
#define INDP  896   // 784 padded to 14*64 (even # of 64-wide K-tiles)
#define OUTD  10

typedef _Float16 f16;
typedef __attribute__((ext_vector_type(8))) _Float16 f16x8;
typedef __attribute__((ext_vector_type(4))) _Float16 f16x4;
typedef __attribute__((ext_vector_type(4))) float f32x4;

// ---- fused segmented prep (R13/R14, verified) ------------------------------
struct PrepArgs {
    const float* src[6];
    const void*  mk[6];
    f16*         dst[6];
    long         off4[7];
    int          rin[6], kin[6], kout[6];
};

__global__ void prep_fused(PrepArgs a, long total4) {
    long idx = (long)blockIdx.x * blockDim.x + threadIdx.x;
    if (idx >= total4) return;
    int s = 0;
    #pragma unroll
    for (int i = 1; i < 6; ++i) s += (idx >= a.off4[i]);
    long li = idx - a.off4[s];
    int kout = a.kout[s], kin = a.kin[s], rin = a.rin[s];
    int k4 = kout >> 2;
    int r = (int)(li / k4), c = (int)(li - (long)r * k4) << 2;
    f16x4 o = {};
    if (r < rin && c < kin) {
        float4 v = *(const float4*)(a.src[s] + (size_t)r * kin + c);
        float vv0 = v.x, vv1 = v.y, vv2 = v.z, vv3 = v.w;
        if (a.mk[s]) {
            uint4 m = *(const uint4*)((const unsigned int*)a.mk[s] + (size_t)r * kin + c);
            if (!m.x) vv0 = 0.f; if (!m.y) vv1 = 0.f;
            if (!m.z) vv2 = 0.f; if (!m.w) vv3 = 0.f;
        }
        o[0] = (f16)vv0; o[1] = (f16)vv1; o[2] = (f16)vv2; o[3] = (f16)vv3;
    }
    *(f16x4*)(a.dst[s] + (size_t)r * kout + c) = o;
}

__device__ __forceinline__ void gload_lds16(const f16* g, f16* l) {
    __builtin_amdgcn_global_load_lds(
        (const __attribute__((address_space(1))) unsigned int*)g,
        (__attribute__((address_space(3))) unsigned int*)l,
        16, 0, 0);
}

#define BAR()    __builtin_amdgcn_s_barrier()
#define SCHED()  __builtin_amdgcn_sched_barrier(0)
#define WAITV0() asm volatile("s_waitcnt vmcnt(0)" ::: "memory")
#define WAITV4() asm volatile("s_waitcnt vmcnt(4)" ::: "memory")
#define WAITV8() asm volatile("s_waitcnt vmcnt(8)" ::: "memory")

// ---- 256x256 4-phase straddle GEMM (R17) -----------------------------------
// R14 (8-phase straddle, 48% MfmaUtil): per-K-tile overhead ~1760 cyc is
// sync/issue (LDS reads only ~770 cyc at 256B/clk -- NOT co-bottleneck).
// R17: merge ks-phases -> 4 phases / 2 K-tiles (barriers 8->4), 32 MFMA per
// phase; frag sets span both ks panels (Aa/Ab/Ba/Bb = 32 b128 = 128 VGPR).
// Stage slots: P2=B(b0)<-t2, P3=A(b0)<-t2, P4=A+B(b1)<-t3 (WAR spacing >=2
// phases except b1-restage at +1 phase + barrier + ~900cy gload landing).
// vmcnt ledger: P1-end vmcnt(0) (all outstanding >=1 phase old, ~free);
// P3-end vmcnt(4) (drains P2's B(b0) for P4's Ba-read); P4-end vmcnt(8)
// (drains P3's A(b0) for next-P1's self-read). Swizzle/staging = R14
// (verified conflict-free). No setprio (R13->R14 A/B).
template<bool RELU>
__global__ __launch_bounds__(512, 2) void gemm8p(
    const f16* __restrict__ A, const f16* __restrict__ B,
    const float* __restrict__ bias, f16* __restrict__ C,
    int N, int K) {
    __shared__ f16 As[2 * 2 * 256 * 32];
    __shared__ f16 Bs[2 * 2 * 256 * 32];

    int nbn = N >> 8;
    int nwg = gridDim.x;
    int cpx = nwg >> 3;                       // nwg % 8 == 0
    int bid = blockIdx.x;
    int swz = (bid & 7) * cpx + (bid >> 3);   // XCD-aware, bijective
    int bm = swz / nbn, bn = swz % nbn;

    int tid = threadIdx.x;
    int w = tid >> 6, lane = tid & 63;
    int wr = w >> 2, wc = w & 3;
    int l15 = lane & 15, l4 = lane >> 4;

    const f16* Ag = A + (size_t)bm * 256 * K;
    const f16* Bg = B + (size_t)bn * 256 * K;

    int r0 = tid >> 2, s0 = tid & 3;
    int c0 = (s0 ^ ((r0 >> 1) & 3)) * 8;
    int ldsw0 = (w * 64) * 8;
    int ldsw1 = (512 + w * 64) * 8;

    auto stageA = [&](int buf, int ks, int tk) {
        gload_lds16(Ag + (size_t)r0 * K + tk * 64 + ks * 32 + c0,
                    As + (buf * 2 + ks) * 8192 + ldsw0);
        gload_lds16(Ag + (size_t)(128 + r0) * K + tk * 64 + ks * 32 + c0,
                    As + (buf * 2 + ks) * 8192 + ldsw1);
    };
    auto stageB = [&](int buf, int ks, int tk) {
        gload_lds16(Bg + (size_t)r0 * K + tk * 64 + ks * 32 + c0,
                    Bs + (buf * 2 + ks) * 8192 + ldsw0);
        gload_lds16(Bg + (size_t)(128 + r0) * K + tk * 64 + ks * 32 + c0,
                    Bs + (buf * 2 + ks) * 8192 + ldsw1);
    };

    int rsw = (l4 ^ ((l15 >> 1) & 3)) * 8;    // R11-verified conflict-free
    auto ldA8 = [&](f16x8 (&af)[8], int buf, int mh) {
        #pragma unroll
        for (int m = 0; m < 4; ++m)
            #pragma unroll
            for (int ks = 0; ks < 2; ++ks) {
                int row = wr * 128 + (mh * 4 + m) * 16 + l15;
                af[m * 2 + ks] = *(const f16x8*)(As + (buf * 2 + ks) * 8192 + row * 32 + rsw);
            }
    };
    auto ldB8 = [&](f16x8 (&bf)[8], int buf) {
        #pragma unroll
        for (int n = 0; n < 4; ++n)
            #pragma unroll
            for (int ks = 0; ks < 2; ++ks) {
                int row = wc * 64 + n * 16 + l15;
                bf[n * 2 + ks] = *(const f16x8*)(Bs + (buf * 2 + ks) * 8192 + row * 32 + rsw);
            }
    };

    f32x4 acc[8][4] = {};
    auto mma8 = [&](f16x8 (&af)[8], f16x8 (&bf)[8], int mh) {
        #pragma unroll
        for (int m = 0; m < 4; ++m)
            #pragma unroll
            for (int n = 0; n < 4; ++n)
                #pragma unroll
                for (int ks = 0; ks < 2; ++ks)
                    acc[mh * 4 + m][n] = __builtin_amdgcn_mfma_f32_16x16x32_f16(
                        af[m * 2 + ks], bf[n * 2 + ks], acc[mh * 4 + m][n], 0, 0, 0);
    };

    int NT = K >> 6, NI = NT >> 1;

    f16x8 Aa[8], Ab[8], Ba[8], Bb[8];

    // prologue: stage b0<-t0 (8), b1<-t1 (8); vmcnt(8) drains b0 keeps b1
    // (b1 drained at P1-end vmcnt(0), 1 phase later); read Ba<-B(b0).
    stageA(0, 0, 0); stageA(0, 1, 0); stageB(0, 0, 0); stageB(0, 1, 0);
    stageA(1, 0, 1); stageA(1, 1, 1); stageB(1, 0, 1); stageB(1, 1, 1);
    WAITV8(); SCHED(); BAR();
    ldB8(Ba, 0);

    for (int it = 0; it < NI; ++it) {
        int t2 = 2 * it + 2, t3 = 2 * it + 3;
        if (t2 >= NT) t2 = 0;   // tail: stage into retired panels, never read
        if (t3 >= NT) t3 = 0;

        // P1: mma(b0,mh0)[Aa,Ba] | self-read Aa<-(b0,mh0) + Ab<-(b0,mh1)
        ldA8(Aa, 0, 0); ldA8(Ab, 0, 1);
        mma8(Aa, Ba, 0);
        WAITV0(); SCHED(); BAR();
        // P2: mma(b0,mh1)[Ab,Ba] | read Aa<-(b1,mh0), Bb<-(b1) | stage B(b0)<-t2
        mma8(Ab, Ba, 1);
        ldA8(Aa, 1, 0); ldB8(Bb, 1); stageB(0, 0, t2); stageB(0, 1, t2);
        SCHED(); BAR();
        // P3: mma(b1,mh0)[Aa,Bb] | read Ab<-(b1,mh1) | stage A(b0)<-t2 | vmcnt(4)
        mma8(Aa, Bb, 0);
        ldA8(Ab, 1, 1); stageA(0, 0, t2); stageA(0, 1, t2);
        WAITV4(); SCHED(); BAR();
        // P4: mma(b1,mh1)[Ab,Bb] | read Ba<-(b0)@t2 | stage A+B(b1)<-t3 | vmcnt(8)
        mma8(Ab, Bb, 1);
        ldB8(Ba, 0);
        stageA(1, 0, t3); stageA(1, 1, t3); stageB(1, 0, t3); stageB(1, 1, t3);
        WAITV8(); SCHED(); BAR();
    }

    // epilogue: C/D layout col=lane&15, row=(lane>>4)*4+reg (m89/m91)
    #pragma unroll
    for (int nf = 0; nf < 4; ++nf) {
        int j = bn * 256 + wc * 64 + nf * 16 + l15;
        float bv = bias[j];
        #pragma unroll
        for (int mf = 0; mf < 8; ++mf) {
            int i0 = bm * 256 + wr * 128 + mf * 16 + l4 * 4;
            #pragma unroll
            for (int r = 0; r < 4; ++r) {
                float v = acc[mf][nf][r] + bv;
                if (RELU) v = fmaxf(v, 0.f);
                C[(size_t)(i0 + r) * N + j] = (f16)v;
            }
        }
    }
}

// ---- head: verified R5 128^2 kernel (Nout=10 guard, f32 out) ---------------
__global__ __launch_bounds__(256, 3) void gemm_head(
    const f16* __restrict__ A, const f16* __restrict__ B,
    const float* __restrict__ bias, float* __restrict__ C,
    int K, int Nout) {
    __shared__ f16 As[128 * 64];
    __shared__ f16 Bs[128 * 64];
    int bm = blockIdx.x;
    int t = threadIdx.x;
    int w = t >> 6, lane = t & 63;
    int wm = w >> 1, wn = w & 1;
    int l15 = lane & 15, l4 = lane >> 4;
    const f16* Ag = A + (size_t)bm * 128 * K;
    const f16* Bg = B;
    int rr = w * 8 + (lane >> 3);
    int cc = (lane & 7) * 8;
    f32x4 acc[4][4] = {};
    for (int k0 = 0; k0 < K; k0 += 64) {
        #pragma unroll
        for (int i = 0; i < 4; ++i)
            gload_lds16(Ag + (size_t)(i * 32 + rr) * K + k0 + cc, As + i * 2048 + w * 512);
        #pragma unroll
        for (int i = 0; i < 4; ++i)
            gload_lds16(Bg + (size_t)(i * 32 + rr) * K + k0 + cc, Bs + i * 2048 + w * 512);
        __syncthreads();
        #pragma unroll
        for (int ks = 0; ks < 2; ++ks) {
            f16x8 af[4], bfr[4];
            #pragma unroll
            for (int m = 0; m < 4; ++m)
                af[m] = *(const f16x8*)(As + (wm * 64 + m * 16 + l15) * 64 + ks * 32 + l4 * 8);
            #pragma unroll
            for (int n = 0; n < 4; ++n)
                bfr[n] = *(const f16x8*)(Bs + (wn * 64 + n * 16 + l15) * 64 + ks * 32 + l4 * 8);
            #pragma unroll
            for (int m = 0; m < 4; ++m)
                #pragma unroll
                for (int n = 0; n < 4; ++n)
                    acc[m][n] = __builtin_amdgcn_mfma_f32_16x16x32_f16(af[m], bfr[n], acc[m][n], 0, 0, 0);
        }
        __syncthreads();
    }
    #pragma unroll
    for (int n = 0; n < 4; ++n) {
        int j = wn * 64 + n * 16 + l15;
        bool jok = j < Nout;
        float bv = jok ? bias[j] : 0.f;
        #pragma unroll
        for (int m = 0; m < 4; ++m) {
            int i0 = bm * 128 + wm * 64 + m * 16 + l4 * 4;
            #pragma unroll
            for (int r = 0; r < 4; ++r) {
                if (jok) C[(size_t)(i0 + r) * Nout + j] = acc[m][n][r] + bv;
            }
        }
    }
}

extern "C" void kernel_launch(void* const* d_in, const int* in_sizes, int n_in,
                              void* d_out, int out_size, void* d_ws, size_t ws_size,
                              hipStream_t stream) {
    const float* x  = (const float*)d_in[0];
    const float* W1 = (const float*)d_in[1];
    const float* b1 = (const float*)d_in[2];
    const float* W2 = (const float*)d_in[3];
    const float* b2 = (const float*)d_in[4];
    const float* W3 = (const float*)d_in[5];
    const float* b3 = (const float*)d_in[6];
    const float* W4 = (const float*)d_in[7];
    const float* b4 = (const float*)d_in[8];
    const float* W5 = (const float*)d_in[9];
    const float* b5 = (const float*)d_in[10];
    const void* m1 = d_in[11];
    const void* m2 = d_in[12];
    const void* m3 = d_in[13];
    const void* m4 = d_in[14];

    char* ws = (char*)d_ws;
    size_t off = 0;
    auto alloc = [&](size_t b) { char* p = ws + off; off += (b + 255) & ~(size_t)255; return p; };
    f16* xb  = (f16*)alloc((size_t)BATCH * INDP * 2);
    f16* w1b = (f16*)alloc((size_t)HID * INDP * 2);
    f16* w2b = (f16*)alloc((size_t)HID * HID * 2);
    f16* w3b = (f16*)alloc((size_t)HID * HID * 2);
    f16* w4b = (f16*)alloc((size_t)HID * HID * 2);
    f16* w5b = (f16*)alloc((size_t)128 * HID * 2);
    f16* h1  = (f16*)alloc((size_t)BATCH * HID * 2);
    f16* h2  = (f16*)alloc((size_t)BATCH * HID * 2);

    PrepArgs pa;
    auto seg = [&](int i, const float* s, const void* mk, f16* d,
                   int rin, int kin, int kout) {
        pa.src[i] = s; pa.mk[i] = mk; pa.dst[i] = d;
        pa.rin[i] = rin; pa.kin[i] = kin; pa.kout[i] = kout;
    };
    seg(0, x,  nullptr, xb,  BATCH, IND, INDP);
    seg(1, W1, m1,      w1b, HID,   IND, INDP);
    seg(2, W2, m2,      w2b, HID,   HID, HID);
    seg(3, W3, m3,      w3b, HID,   HID, HID);
    seg(4, W4, m4,      w4b, HID,   HID, HID);
    seg(5, W5, nullptr, w5b, OUTD,  HID, HID);
    long rout[6] = {BATCH, HID, HID, HID, HID, 128};
    long acc4 = 0;
    for (int i = 0; i < 6; ++i) { pa.off4[i] = acc4; acc4 += rout[i] * (pa.kout[i] >> 2); }
    pa.off4[6] = acc4;
    int pgrid = (int)((acc4 + 255) / 256);
    prep_fused<<<pgrid, 256, 0, stream>>>(pa, acc4);

    int g8 = (BATCH / 256) * (HID / 256);   // 64 * 8 = 512 blocks
    gemm8p<true><<<g8, 512, 0, stream>>>(xb, w1b, b1, h1, HID, INDP);
    gemm8p<true><<<g8, 512, 0, stream>>>(h1, w2b, b2, h2, HID, HID);
    gemm8p<true><<<g8, 512, 0, stream>>>(h2, w3b, b3, h1, HID, HID);
    gemm8p<true><<<g8, 512, 0, stream>>>(h1, w4b, b4, h2, HID, HID);
    gemm_head<<<BATCH / 128, 256, 0, stream>>>(h2, w5b, b5, (float*)d_out, HID, OUTD);
}

// Round 18
// 486.056 us; speedup vs baseline: 1.2404x; 1.0443x over previous
//
#include <hip/hip_runtime.h>
#include <hip/hip_bf16.h>
#include <hip/hip_fp16.h>

#define BATCH 16384
#define HID   2048
#define IND   784
#define INDP  896   // 784 padded to 14*64 (even # of 64-wide K-tiles)
#define OUTD  10

typedef _Float16 f16;
typedef __attribute__((ext_vector_type(8))) _Float16 f16x8;
typedef __attribute__((ext_vector_type(4))) _Float16 f16x4;
typedef __attribute__((ext_vector_type(4))) float f32x4;

// ---- fused segmented prep (R13/R14, verified) ------------------------------
struct PrepArgs {
    const float* src[6];
    const void*  mk[6];
    f16*         dst[6];
    long         off4[7];
    int          rin[6], kin[6], kout[6];
};

__global__ void prep_fused(PrepArgs a, long total4) {
    long idx = (long)blockIdx.x * blockDim.x + threadIdx.x;
    if (idx >= total4) return;
    int s = 0;
    #pragma unroll
    for (int i = 1; i < 6; ++i) s += (idx >= a.off4[i]);
    long li = idx - a.off4[s];
    int kout = a.kout[s], kin = a.kin[s], rin = a.rin[s];
    int k4 = kout >> 2;
    int r = (int)(li / k4), c = (int)(li - (long)r * k4) << 2;
    f16x4 o = {};
    if (r < rin && c < kin) {
        float4 v = *(const float4*)(a.src[s] + (size_t)r * kin + c);
        float vv0 = v.x, vv1 = v.y, vv2 = v.z, vv3 = v.w;
        if (a.mk[s]) {
            uint4 m = *(const uint4*)((const unsigned int*)a.mk[s] + (size_t)r * kin + c);
            if (!m.x) vv0 = 0.f; if (!m.y) vv1 = 0.f;
            if (!m.z) vv2 = 0.f; if (!m.w) vv3 = 0.f;
        }
        o[0] = (f16)vv0; o[1] = (f16)vv1; o[2] = (f16)vv2; o[3] = (f16)vv3;
    }
    *(f16x4*)(a.dst[s] + (size_t)r * kout + c) = o;
}

__device__ __forceinline__ void gload_lds16(const f16* g, f16* l) {
    __builtin_amdgcn_global_load_lds(
        (const __attribute__((address_space(1))) unsigned int*)g,
        (__attribute__((address_space(3))) unsigned int*)l,
        16, 0, 0);
}

#define BAR()    __builtin_amdgcn_s_barrier()
#define SCHED()  __builtin_amdgcn_sched_barrier(0)
#define WAITV4() asm volatile("s_waitcnt vmcnt(4)" ::: "memory")
#define WAITV8() asm volatile("s_waitcnt vmcnt(8)" ::: "memory")

// ---- 256x256 8-phase GEMM, depth-2 straddling pipeline (R14, best) ---------
// Verified best: ~120 us/layer, MfmaUtil 48.3%, conflicts 0, absmax 1.22e-4.
// Straddle: phase p's mma consumes frags issued at p-2 (compiler inserts the
// counted lgkmcnt before the mfma, two barriers downstream of the read issue
// -> reads drain under other phases' MFMA). No setprio (R13->R14 A/B: +2%).
// Counted vmcnt(4) at even phase ends; every stage has ~3 phases (~1770 cyc)
// to land vs ~900 cyc HBM latency -> drains are free. Swizzle: 16B-slot ^=
// ((row>>1)&3) on both staging source and ds_read (involution; conflict-free
// verified R7: SQ_LDS_BANK_CONFLICT 1.26e7 -> 0).
// Design-space log (us/layer | MfmaUtil): R7 lockstep+uniform 135|42.4;
// R14 (this) 120|48.3; R15 lockstep+quadrant 134|42.7; R16 128^2 2blk/CU
// 162|36.4; R17 4-phase 130|43.0. Residual ~50% is barrier-rendezvous
// overhead; resisted barrier-halving at 16->8 (null) and 8->4 (regression).
template<bool RELU>
__global__ __launch_bounds__(512, 2) void gemm8p(
    const f16* __restrict__ A, const f16* __restrict__ B,
    const float* __restrict__ bias, f16* __restrict__ C,
    int N, int K) {
    __shared__ f16 As[2 * 2 * 256 * 32];
    __shared__ f16 Bs[2 * 2 * 256 * 32];

    int nbn = N >> 8;
    int nwg = gridDim.x;
    int cpx = nwg >> 3;                       // nwg % 8 == 0 here
    int bid = blockIdx.x;
    int swz = (bid & 7) * cpx + (bid >> 3);   // XCD-aware, bijective
    int bm = swz / nbn, bn = swz % nbn;

    int tid = threadIdx.x;
    int w = tid >> 6, lane = tid & 63;
    int wr = w >> 2, wc = w & 3;
    int l15 = lane & 15, l4 = lane >> 4;

    const f16* Ag = A + (size_t)bm * 256 * K;
    const f16* Bg = B + (size_t)bn * 256 * K;

    int r0 = tid >> 2, s0 = tid & 3;
    int c0 = (s0 ^ ((r0 >> 1) & 3)) * 8;
    int ldsw0 = (w * 64) * 8;
    int ldsw1 = (512 + w * 64) * 8;

    auto stageA = [&](int buf, int ks, int tk) {
        gload_lds16(Ag + (size_t)r0 * K + tk * 64 + ks * 32 + c0,
                    As + (buf * 2 + ks) * 8192 + ldsw0);
        gload_lds16(Ag + (size_t)(128 + r0) * K + tk * 64 + ks * 32 + c0,
                    As + (buf * 2 + ks) * 8192 + ldsw1);
    };
    auto stageB = [&](int buf, int ks, int tk) {
        gload_lds16(Bg + (size_t)r0 * K + tk * 64 + ks * 32 + c0,
                    Bs + (buf * 2 + ks) * 8192 + ldsw0);
        gload_lds16(Bg + (size_t)(128 + r0) * K + tk * 64 + ks * 32 + c0,
                    Bs + (buf * 2 + ks) * 8192 + ldsw1);
    };

    int rsw = (l4 ^ ((l15 >> 1) & 3)) * 8;    // swizzled read slot (f16 units)
    auto ldA = [&](f16x8 (&af)[4], int buf, int ks, int mh) {
        int base = (buf * 2 + ks) * 8192;
        #pragma unroll
        for (int m = 0; m < 4; ++m) {
            int row = wr * 128 + (mh * 4 + m) * 16 + l15;
            af[m] = *(const f16x8*)(As + base + row * 32 + rsw);
        }
    };
    auto ldB = [&](f16x8 (&bf)[4], int buf, int ks) {
        int base = (buf * 2 + ks) * 8192;
        #pragma unroll
        for (int n = 0; n < 4; ++n) {
            int row = wc * 64 + n * 16 + l15;
            bf[n] = *(const f16x8*)(Bs + base + row * 32 + rsw);
        }
    };

    f32x4 acc[8][4] = {};
    auto mma = [&](f16x8 (&af)[4], f16x8 (&bf)[4], int mh) {
        #pragma unroll
        for (int m = 0; m < 4; ++m)
            #pragma unroll
            for (int n = 0; n < 4; ++n)
                acc[mh * 4 + m][n] = __builtin_amdgcn_mfma_f32_16x16x32_f16(
                    af[m], bf[n], acc[mh * 4 + m][n], 0, 0, 0);
    };

    int NT = K >> 6, NI = NT >> 1;

    f16x8 Aa[4], Ab[4], Ba[4], Bb[4];

    stageA(0, 0, 0); stageB(0, 0, 0); stageA(0, 1, 0); stageB(0, 1, 0);
    stageA(1, 0, 1); stageB(1, 0, 1);
    WAITV8(); SCHED(); BAR();
    ldA(Aa, 0, 0, 0); ldB(Bb, 0, 0); ldA(Ab, 0, 0, 1);
    WAITV4(); SCHED(); BAR();

    for (int it = 0; it < NI; ++it) {
        int t1 = 2 * it + 1, t2 = 2 * it + 2, t3 = 2 * it + 3;
        if (t2 >= NT) t2 = 0;   // tail: stage into retired panels, never used
        if (t3 >= NT) t3 = 0;

        // p1: mma (0,0,mh0)[Aa,Bb] | read p3: Aa<-(0,1,m0), Ba<-(0,1) | stage A(1,1)<-t1
        mma(Aa, Bb, 0);
        ldA(Aa, 0, 1, 0); ldB(Ba, 0, 1); stageA(1, 1, t1);
        SCHED(); BAR();
        // p2: mma (0,0,mh1)[Ab,Bb] | read p4: Ab<-(0,1,m1) | stage B(1,1)<-t1 | vmcnt
        mma(Ab, Bb, 1);
        ldA(Ab, 0, 1, 1); stageB(1, 1, t1);
        WAITV4(); SCHED(); BAR();
        // p3: mma (0,1,mh0)[Aa,Ba] | read p5: Aa<-(1,0,m0), Bb<-(1,0) | stage A(0,0)<-t2
        mma(Aa, Ba, 0);
        ldA(Aa, 1, 0, 0); ldB(Bb, 1, 0); stageA(0, 0, t2);
        SCHED(); BAR();
        // p4: mma (0,1,mh1)[Ab,Ba] | read p6: Ab<-(1,0,m1) | stage B(0,0)<-t2 | vmcnt
        mma(Ab, Ba, 1);
        ldA(Ab, 1, 0, 1); stageB(0, 0, t2);
        WAITV4(); SCHED(); BAR();
        // p5: mma (1,0,mh0)[Aa,Bb] | read p7: Aa<-(1,1,m0), Ba<-(1,1) | stage A(0,1)<-t2
        mma(Aa, Bb, 0);
        ldA(Aa, 1, 1, 0); ldB(Ba, 1, 1); stageA(0, 1, t2);
        SCHED(); BAR();
        // p6: mma (1,0,mh1)[Ab,Bb] | read p8: Ab<-(1,1,m1) | stage B(0,1)<-t2 | vmcnt
        mma(Ab, Bb, 1);
        ldA(Ab, 1, 1, 1); stageB(0, 1, t2);
        WAITV4(); SCHED(); BAR();
        // p7: mma (1,1,mh0)[Aa,Ba] | read p1': Aa<-(0,0,m0), Bb<-(0,0) | stage A(1,0)<-t3
        mma(Aa, Ba, 0);
        ldA(Aa, 0, 0, 0); ldB(Bb, 0, 0); stageA(1, 0, t3);
        SCHED(); BAR();
        // p8: mma (1,1,mh1)[Ab,Ba] | read p2': Ab<-(0,0,m1) | stage B(1,0)<-t3 | vmcnt
        mma(Ab, Ba, 1);
        ldA(Ab, 0, 0, 1); stageB(1, 0, t3);
        WAITV4(); SCHED(); BAR();
    }

    // epilogue: C/D layout col=lane&15, row=(lane>>4)*4+reg (m89/m91)
    #pragma unroll
    for (int nf = 0; nf < 4; ++nf) {
        int j = bn * 256 + wc * 64 + nf * 16 + l15;
        float bv = bias[j];
        #pragma unroll
        for (int mf = 0; mf < 8; ++mf) {
            int i0 = bm * 256 + wr * 128 + mf * 16 + l4 * 4;
            #pragma unroll
            for (int r = 0; r < 4; ++r) {
                float v = acc[mf][nf][r] + bv;
                if (RELU) v = fmaxf(v, 0.f);
                C[(size_t)(i0 + r) * N + j] = (f16)v;
            }
        }
    }
}

// ---- head: verified R5 128^2 kernel (Nout=10 guard, f32 out) ---------------
__global__ __launch_bounds__(256, 3) void gemm_head(
    const f16* __restrict__ A, const f16* __restrict__ B,
    const float* __restrict__ bias, float* __restrict__ C,
    int K, int Nout) {
    __shared__ f16 As[128 * 64];
    __shared__ f16 Bs[128 * 64];
    int bm = blockIdx.x;
    int t = threadIdx.x;
    int w = t >> 6, lane = t & 63;
    int wm = w >> 1, wn = w & 1;
    int l15 = lane & 15, l4 = lane >> 4;
    const f16* Ag = A + (size_t)bm * 128 * K;
    const f16* Bg = B;
    int rr = w * 8 + (lane >> 3);
    int cc = (lane & 7) * 8;
    f32x4 acc[4][4] = {};
    for (int k0 = 0; k0 < K; k0 += 64) {
        #pragma unroll
        for (int i = 0; i < 4; ++i)
            gload_lds16(Ag + (size_t)(i * 32 + rr) * K + k0 + cc, As + i * 2048 + w * 512);
        #pragma unroll
        for (int i = 0; i < 4; ++i)
            gload_lds16(Bg + (size_t)(i * 32 + rr) * K + k0 + cc, Bs + i * 2048 + w * 512);
        __syncthreads();
        #pragma unroll
        for (int ks = 0; ks < 2; ++ks) {
            f16x8 af[4], bfr[4];
            #pragma unroll
            for (int m = 0; m < 4; ++m)
                af[m] = *(const f16x8*)(As + (wm * 64 + m * 16 + l15) * 64 + ks * 32 + l4 * 8);
            #pragma unroll
            for (int n = 0; n < 4; ++n)
                bfr[n] = *(const f16x8*)(Bs + (wn * 64 + n * 16 + l15) * 64 + ks * 32 + l4 * 8);
            #pragma unroll
            for (int m = 0; m < 4; ++m)
                #pragma unroll
                for (int n = 0; n < 4; ++n)
                    acc[m][n] = __builtin_amdgcn_mfma_f32_16x16x32_f16(af[m], bfr[n], acc[m][n], 0, 0, 0);
        }
        __syncthreads();
    }
    #pragma unroll
    for (int n = 0; n < 4; ++n) {
        int j = wn * 64 + n * 16 + l15;
        bool jok = j < Nout;
        float bv = jok ? bias[j] : 0.f;
        #pragma unroll
        for (int m = 0; m < 4; ++m) {
            int i0 = bm * 128 + wm * 64 + m * 16 + l4 * 4;
            #pragma unroll
            for (int r = 0; r < 4; ++r) {
                if (jok) C[(size_t)(i0 + r) * Nout + j] = acc[m][n][r] + bv;
            }
        }
    }
}

extern "C" void kernel_launch(void* const* d_in, const int* in_sizes, int n_in,
                              void* d_out, int out_size, void* d_ws, size_t ws_size,
                              hipStream_t stream) {
    const float* x  = (const float*)d_in[0];
    const float* W1 = (const float*)d_in[1];
    const float* b1 = (const float*)d_in[2];
    const float* W2 = (const float*)d_in[3];
    const float* b2 = (const float*)d_in[4];
    const float* W3 = (const float*)d_in[5];
    const float* b3 = (const float*)d_in[6];
    const float* W4 = (const float*)d_in[7];
    const float* b4 = (const float*)d_in[8];
    const float* W5 = (const float*)d_in[9];
    const float* b5 = (const float*)d_in[10];
    const void* m1 = d_in[11];
    const void* m2 = d_in[12];
    const void* m3 = d_in[13];
    const void* m4 = d_in[14];

    char* ws = (char*)d_ws;
    size_t off = 0;
    auto alloc = [&](size_t b) { char* p = ws + off; off += (b + 255) & ~(size_t)255; return p; };
    f16* xb  = (f16*)alloc((size_t)BATCH * INDP * 2);
    f16* w1b = (f16*)alloc((size_t)HID * INDP * 2);
    f16* w2b = (f16*)alloc((size_t)HID * HID * 2);
    f16* w3b = (f16*)alloc((size_t)HID * HID * 2);
    f16* w4b = (f16*)alloc((size_t)HID * HID * 2);
    f16* w5b = (f16*)alloc((size_t)128 * HID * 2);
    f16* h1  = (f16*)alloc((size_t)BATCH * HID * 2);
    f16* h2  = (f16*)alloc((size_t)BATCH * HID * 2);

    PrepArgs pa;
    auto seg = [&](int i, const float* s, const void* mk, f16* d,
                   int rin, int kin, int kout) {
        pa.src[i] = s; pa.mk[i] = mk; pa.dst[i] = d;
        pa.rin[i] = rin; pa.kin[i] = kin; pa.kout[i] = kout;
    };
    seg(0, x,  nullptr, xb,  BATCH, IND, INDP);
    seg(1, W1, m1,      w1b, HID,   IND, INDP);
    seg(2, W2, m2,      w2b, HID,   HID, HID);
    seg(3, W3, m3,      w3b, HID,   HID, HID);
    seg(4, W4, m4,      w4b, HID,   HID, HID);
    seg(5, W5, nullptr, w5b, OUTD,  HID, HID);
    long rout[6] = {BATCH, HID, HID, HID, HID, 128};
    long acc4 = 0;
    for (int i = 0; i < 6; ++i) { pa.off4[i] = acc4; acc4 += rout[i] * (pa.kout[i] >> 2); }
    pa.off4[6] = acc4;
    int pgrid = (int)((acc4 + 255) / 256);
    prep_fused<<<pgrid, 256, 0, stream>>>(pa, acc4);

    int g8 = (BATCH / 256) * (HID / 256);   // 64 * 8 = 512 blocks
    gemm8p<true><<<g8, 512, 0, stream>>>(xb, w1b, b1, h1, HID, INDP);
    gemm8p<true><<<g8, 512, 0, stream>>>(h1, w2b, b2, h2, HID, HID);
    gemm8p<true><<<g8, 512, 0, stream>>>(h2, w3b, b3, h1, HID, HID);
    gemm8p<true><<<g8, 512, 0, stream>>>(h1, w4b, b4, h2, HID, HID);
    gemm_head<<<BATCH / 128, 256, 0, stream>>>(h2, w5b, b5, (float*)d_out, HID, OUTD);
}